// Round 11
// baseline (122.336 us; speedup 1.0000x reference)
//
#include <hip/hip_runtime.h>
#include <hip/hip_bf16.h>
#include <stdint.h>

typedef __attribute__((ext_vector_type(8))) short bf8;
typedef __attribute__((ext_vector_type(4))) short bf4;
typedef __attribute__((ext_vector_type(4))) float f32x4;

#define MFMA16(a,b,c) __builtin_amdgcn_mfma_f32_16x16x32_bf16(a,b,c,0,0,0)

// LDS-only barrier: ds-ops drained, but in-flight global loads (prefetch)
// SURVIVE the barrier -- unlike __syncthreads' vmcnt(0) drain.
__device__ __forceinline__ void barrier_lds(){
  asm volatile("s_waitcnt lgkmcnt(0)\n\ts_barrier" ::: "memory");
  __builtin_amdgcn_sched_barrier(0);
}

__device__ __forceinline__ unsigned short f2bf(float x){
  unsigned int u = __builtin_bit_cast(unsigned int, x);
  u = u + 0x7FFFu + ((u >> 16) & 1u);
  return (unsigned short)(u >> 16);
}
__device__ __forceinline__ unsigned short f2bfb(float x){
  __hip_bfloat16 h = __float2bfloat16(x);
  return __builtin_bit_cast(unsigned short, h);
}
__device__ __forceinline__ float bf2f(unsigned short h){
  unsigned int u = ((unsigned int)h) << 16;
  return __builtin_bit_cast(float, u);
}
// fast sigmoid: no precise-div refinement
__device__ __forceinline__ float sigm(float x){
  return __builtin_amdgcn_rcpf(1.0f + __expf(-x));
}
// swizzled u16 element index for row-major [R][K] bf16 tile, Kd8 = K/8
__device__ __forceinline__ int swzu(int row, int k, int Kd8){
  return (row*Kd8 + ((k>>3) ^ (row & 7)))*8 + (k & 7);
}

// ---- LDS-tiled 64x64 transpose: out[j*R + k] = bf16(in[k*C + j]) ----
__device__ __forceinline__ void tile_transpose(const float* __restrict__ in,
                                               unsigned short* __restrict__ out,
                                               int R, int C, int tb,
                                               float* tile, int tid)
{
  int nkt = R >> 6;
  int kt = tb % nkt, jt = tb / nkt;
  int r0 = tid >> 4, cs = tid & 15;
  #pragma unroll
  for (int i = 0; i < 4; ++i){
    int r = r0 + i*16;
    float4 v = *(const float4*)(in + (size_t)(kt*64 + r)*C + jt*64 + cs*4);
    tile[r*65 + cs*4 + 0] = v.x;
    tile[r*65 + cs*4 + 1] = v.y;
    tile[r*65 + cs*4 + 2] = v.z;
    tile[r*65 + cs*4 + 3] = v.w;
  }
  __syncthreads();
  int j = tid >> 2, ks = tid & 3;
  bf8 o0, o1;
  #pragma unroll
  for (int e = 0; e < 8; ++e){
    o0[e] = (short)f2bf(tile[(ks*16 + e)*65 + j]);
    o1[e] = (short)f2bf(tile[(ks*16 + 8 + e)*65 + j]);
  }
  *(bf8*)(out + (size_t)(jt*64 + j)*R + kt*64 + ks*16)     = o0;
  *(bf8*)(out + (size_t)(jt*64 + j)*R + kt*64 + ks*16 + 8) = o1;
}

// ---------------- prep: weights + emb table to bf16 ----------------
__global__ void k_prep(const float* __restrict__ aw1, const float* __restrict__ aw2,
                       const float* __restrict__ nw, const float* __restrict__ dw1,
                       const float* __restrict__ dw2, const float* __restrict__ dw3,
                       const float* __restrict__ emb,
                       unsigned short* __restrict__ WbT, unsigned short* __restrict__ WcT,
                       unsigned short* __restrict__ Wsum, unsigned short* __restrict__ A2T,
                       unsigned short* __restrict__ NWT, unsigned short* __restrict__ D1T,
                       unsigned short* __restrict__ D2T, unsigned short* __restrict__ D3T,
                       unsigned short* __restrict__ EMBB)
{
  __shared__ float tile[64*65];
  const int bid = blockIdx.x;
  const int tid = threadIdx.x;

  if (bid < 88){
    if (bid < 48)      tile_transpose(dw1, D1T, 384, 512, bid,      tile, tid);
    else if (bid < 80) tile_transpose(dw2, D2T, 512, 256, bid - 48, tile, tid);
    else               tile_transpose(dw3, D3T, 256, 128, bid - 80, tile, tid);
    return;
  }

  int n = (bid - 88)*256 + tid;
  int stride = (gridDim.x - 88)*256;
  // emb fp32 -> bf16 (1.6M chunks of 8)
  for (int i = n; i < 1600000; i += stride){
    const float4* s = (const float4*)(emb + (size_t)i*8);
    float4 a = s[0], b = s[1];
    bf8 o;
    o[0]=(short)f2bf(a.x); o[1]=(short)f2bf(a.y); o[2]=(short)f2bf(a.z); o[3]=(short)f2bf(a.w);
    o[4]=(short)f2bf(b.x); o[5]=(short)f2bf(b.y); o[6]=(short)f2bf(b.z); o[7]=(short)f2bf(b.w);
    ((bf8*)EMBB)[i] = o;
  }
  for (int i = n; i < 16384; i += stride){       // WbT/WcT: [j][k]
    int j = i >> 7, k = i & 127;
    WbT[i] = f2bf(aw1[(128+k)*128 + j]);
    WcT[i] = f2bf(aw1[(256+k)*128 + j]);
  }
  for (int i = n; i < 16384; i += stride){       // Wsum: [j][k]
    int j = i >> 7, k = i & 127;
    Wsum[i] = f2bf(aw1[k*128 + j] + aw1[(256+k)*128 + j]);
  }
  for (int i = n; i < 8192; i += stride){        // A2T: [j(0..63)][k]
    int j = i >> 7, k = i & 127;
    A2T[i] = f2bf(aw2[k*64 + j]);
  }
  for (int i = n; i < 16384; i += stride){       // NWT: [j][k]
    int j = i >> 7, k = i & 127;
    NWT[i] = f2bf(nw[k*128 + j]);
  }
}

// ---------------- attention: R3 structure + lgkm-only loop barriers ----------------
__global__ __launch_bounds__(256, 4) void k_attn(
    const int* __restrict__ in_ids, const int* __restrict__ item_id,
    const float* __restrict__ emb, const unsigned short* __restrict__ embb,
    const float* __restrict__ ab1, const float* __restrict__ ab2v,
    const float* __restrict__ afw, const float* __restrict__ afb,
    const unsigned short* __restrict__ WbT, const unsigned short* __restrict__ WcT,
    const unsigned short* __restrict__ Wsum, const unsigned short* __restrict__ A2T,
    float* __restrict__ attn_raw)
{
  __shared__ __align__(16) unsigned short sS[32*128];   // seq tile bf16, swizzled
  __shared__ __align__(16) unsigned short sH[32*128];   // h1^T [r][j], swizzled
  __shared__ float sT[128];
  __shared__ float sC0[128];
  __shared__ float sP2[2][128];
  __shared__ float sPart[4][32];
  __shared__ int   sIds[32];

  const int b = blockIdx.x;
  const int tid = threadIdx.x;
  const int wave = tid >> 6, lane = tid & 63;
  const int lr = lane & 15, lg = lane >> 4;

  const int tgt = item_id[b];
  if (tid < 128) sT[tid] = emb[(size_t)tgt*128 + tid];
  __syncthreads();

  // ---- c0[j] = ab1[j] + sum_k t_k * Wsum[j][k] ----
  {
    int j = tid & 127, hf = tid >> 7;
    const unsigned short* wsrow = Wsum + j*128 + hf*64;
    float p = 0.f;
    #pragma unroll
    for (int c = 0; c < 8; ++c){
      bf8 wv = *(const bf8*)(wsrow + c*8);
      #pragma unroll
      for (int e = 0; e < 8; ++e)
        p += sT[hf*64 + c*8 + e] * bf2f((unsigned short)wv[e]);
    }
    sP2[hf][j] = p;
  }
  __syncthreads();
  if (tid < 128) sC0[tid] = ab1[tid] + sP2[0][tid] + sP2[1][tid];

  // ---- W_eff^T A-fragments in registers: W_eff[k][j] = t_k*Wb[k][j]-Wc[k][j]
  bf8 wfrag[2][4];
  {
    const float4* sT4 = (const float4*)sT;
    #pragma unroll
    for (int mt = 0; mt < 2; ++mt){
      int j = (wave + mt*4)*16 + lr;
      #pragma unroll
      for (int kk = 0; kk < 4; ++kk){
        bf8 wb = *(const bf8*)(WbT + j*128 + kk*32 + lg*8);
        bf8 wc = *(const bf8*)(WcT + j*128 + kk*32 + lg*8);
        float4 t0 = sT4[kk*8 + lg*2];
        float4 t1 = sT4[kk*8 + lg*2 + 1];
        float tv[8] = {t0.x,t0.y,t0.z,t0.w,t1.x,t1.y,t1.z,t1.w};
        bf8 o;
        #pragma unroll
        for (int e = 0; e < 8; ++e)
          o[e] = (short)f2bfb(tv[e]*bf2f((unsigned short)wb[e]) - bf2f((unsigned short)wc[e]));
        wfrag[mt][kk] = o;
      }
    }
  }
  bf8 a2frag[4];
  #pragma unroll
  for (int kk = 0; kk < 4; ++kk)
    a2frag[kk] = *(const bf8*)(A2T + (wave*16+lr)*128 + kk*32 + lg*8);

  float b2r[4], afr[4];
  #pragma unroll
  for (int i = 0; i < 4; ++i){
    int j2 = wave*16 + lg*4 + i;
    b2r[i] = ab2v[j2];
    afr[i] = afw[j2];
  }
  const float afbv = afb[0];
  __syncthreads();
  float c0r[2][4];
  #pragma unroll
  for (int mt = 0; mt < 2; ++mt)
    #pragma unroll
    for (int i = 0; i < 4; ++i)
      c0r[mt][i] = sC0[(wave + mt*4)*16 + lg*4 + i];

  float facc8[8] = {0,0,0,0,0,0,0,0};
  const bf8* S8 = (const bf8*)sS;
  const bf8* H8 = (const bf8*)sH;
  const int rg = tid >> 4, cg = tid & 15;
  const int sxm = lr & 7;
  const int chv = tid & 15;
  const int rowq = tid >> 4;              // 0..15

  // ---- prologue: stage tile 0 into registers ----
  bf8 stg0, stg1; int id0, id1;
  {
    id0 = in_ids[b*200 + rowq];
    stg0 = *(const bf8*)(embb + (size_t)id0*128 + chv*8);
    id1 = in_ids[b*200 + 16 + rowq];
    stg1 = *(const bf8*)(embb + (size_t)id1*128 + chv*8);
  }

  for (int rt = 0; rt < 7; ++rt){
    barrier_lds();     // sS/sIds/sPart free (prev tile's LDS reads drained)
    // ---- commit staged tile to LDS (compiler waits exactly these vm loads) ----
    if (chv == 0){ sIds[rowq] = id0; sIds[16 + rowq] = id1; }
    ((bf8*)sS)[rowq*16 + (chv ^ (rowq & 7))] = stg0;
    {
      int r2 = 16 + rowq;
      ((bf8*)sS)[r2*16 + (chv ^ (r2 & 7))] = stg1;
    }
    // ---- issue prefetch for next tile; loads stay in flight across ALL
    //      following lgkm-only barriers => a full tile of latency cover ----
    if (rt < 6){
      int l0 = (rt+1)*32 + rowq;
      id0 = (l0 < 200) ? in_ids[b*200 + l0] : 0;
      stg0 = *(const bf8*)(embb + (size_t)id0*128 + chv*8);
      int l1 = l0 + 16;
      id1 = (l1 < 200) ? in_ids[b*200 + l1] : 0;
      stg1 = *(const bf8*)(embb + (size_t)id1*128 + chv*8);
    }
    barrier_lds();     // sS ready (ds_writes drained; prefetch still flying)
    // ---- GEMM1: h1pre^T = mfma(Wfrag, Sfrag) ----
    f32x4 acc1[2][2] = {};
    #pragma unroll
    for (int kk = 0; kk < 4; ++kk){
      int kx = (kk*4 + lg) ^ sxm;
      bf8 s0 = S8[lr*16 + kx];
      bf8 s1 = S8[(16+lr)*16 + kx];
      acc1[0][0] = MFMA16(wfrag[0][kk], s0, acc1[0][0]);
      acc1[0][1] = MFMA16(wfrag[0][kk], s1, acc1[0][1]);
      acc1[1][0] = MFMA16(wfrag[1][kk], s0, acc1[1][0]);
      acc1[1][1] = MFMA16(wfrag[1][kk], s1, acc1[1][1]);
    }
    // write h1^T quads (4 consecutive j -> ds_write_b64)
    #pragma unroll
    for (int mt = 0; mt < 2; ++mt)
      #pragma unroll
      for (int nt = 0; nt < 2; ++nt){
        int r = nt*16 + lr;
        int j0 = (wave + mt*4)*16 + lg*4;
        bf4 q4;
        #pragma unroll
        for (int i = 0; i < 4; ++i)
          q4[i] = (short)f2bfb(sigm(acc1[mt][nt][i] + c0r[mt][i]));
        int idx = (r*16 + ((j0 >> 3) ^ (r & 7)))*8 + (j0 & 7);
        *(bf4*)(sH + idx) = q4;
      }
    barrier_lds();     // sH ready
    // ---- GEMM2: h2^T = mfma(A2frag, Hfrag); score partials in-register ----
    f32x4 acc2[2] = {};
    #pragma unroll
    for (int kk = 0; kk < 4; ++kk){
      int kx = (kk*4 + lg) ^ sxm;
      bf8 h0 = H8[lr*16 + kx];
      bf8 h1f = H8[(16+lr)*16 + kx];
      acc2[0] = MFMA16(a2frag[kk], h0, acc2[0]);
      acc2[1] = MFMA16(a2frag[kk], h1f, acc2[1]);
    }
    float part0 = 0.f, part1 = 0.f;
    #pragma unroll
    for (int i = 0; i < 4; ++i){
      part0 += sigm(acc2[0][i] + b2r[i]) * afr[i];
      part1 += sigm(acc2[1][i] + b2r[i]) * afr[i];
    }
    part0 += __shfl_xor(part0, 16); part0 += __shfl_xor(part0, 32);
    part1 += __shfl_xor(part1, 16); part1 += __shfl_xor(part1, 32);
    if (lg == 0){ sPart[wave][lr] = part0; sPart[wave][16+lr] = part1; }
    barrier_lds();     // sPart ready
    // ---- attn += score * S ----
    #pragma unroll
    for (int q = 0; q < 2; ++q){
      int r = rg*2 + q;
      int l = rt*32 + r;
      float sc = sPart[0][r] + sPart[1][r] + sPart[2][r] + sPart[3][r] + afbv;
      sc = (l < 200 && sIds[r] != 0) ? sc : 0.f;
      bf8 v = S8[r*16 + (cg ^ (r & 7))];
      #pragma unroll
      for (int e = 0; e < 8; ++e)
        facc8[e] += sc * bf2f((unsigned short)v[e]);
    }
  }
  // ---- final reduce over 16 row-groups (reuse sS as float scratch) ----
  __syncthreads();
  float* red = (float*)sS;
  #pragma unroll
  for (int e = 0; e < 8; ++e) red[tid*8 + e] = facc8[e];
  __syncthreads();
  if (tid < 128){
    float s = 0.f;
    #pragma unroll
    for (int g = 0; g < 16; ++g) s += red[g*128 + tid];
    attn_raw[(size_t)b*128 + tid] = s;
  }
}

// ---------------- deep MLP (512 threads, 8 waves) ----------------
__global__ __launch_bounds__(512) void k_deep(
    const int* __restrict__ item_id, const float* __restrict__ emb,
    const float* __restrict__ bias_tab,
    const float* __restrict__ nbv,
    const float* __restrict__ db1, const float* __restrict__ db2,
    const float* __restrict__ db3, const float* __restrict__ fw,
    const float* __restrict__ fb,
    const unsigned short* __restrict__ NWT, const unsigned short* __restrict__ D1T,
    const unsigned short* __restrict__ D2T, const unsigned short* __restrict__ D3T,
    const float* __restrict__ attn_raw, float* __restrict__ out)
{
  __shared__ __align__(16) unsigned short sA[16*128];
  __shared__ float sTf[16*128];
  __shared__ __align__(16) unsigned short sCat[16*384];
  __shared__ __align__(16) unsigned short sG1[16*512];
  __shared__ __align__(16) unsigned short sG2[16*256];
  __shared__ __align__(16) unsigned short sG3[16*128];
  __shared__ float sNB[128], sDB1[512], sDB2[256], sDB3[128], sFWd[128];
  __shared__ float sBias[16];

  const int r0 = blockIdx.x * 16;
  const int tid = threadIdx.x;
  const int wave = tid >> 6, lane = tid & 63;
  const int lr = lane & 15, lg = lane >> 4;
  const int sx = lr & 7;

  if (tid < 128){ sNB[tid] = nbv[tid]; sDB3[tid] = db3[tid]; sFWd[tid] = fw[tid]; }
  sDB1[tid] = db1[tid];
  if (tid < 256) sDB2[tid] = db2[tid];
  if (tid < 16) sBias[tid] = bias_tab[item_id[r0 + tid]];

  if (tid < 256){
    int r = tid >> 4, ch = tid & 15;
    const float* asrc = attn_raw + (size_t)(r0 + r)*128 + ch*8;
    float4 v0 = *(const float4*)asrc;
    float4 v1 = *(const float4*)(asrc + 4);
    bf8 o;
    o[0]=(short)f2bf(v0.x); o[1]=(short)f2bf(v0.y); o[2]=(short)f2bf(v0.z); o[3]=(short)f2bf(v0.w);
    o[4]=(short)f2bf(v1.x); o[5]=(short)f2bf(v1.y); o[6]=(short)f2bf(v1.z); o[7]=(short)f2bf(v1.w);
    ((bf8*)sA)[r*16 + (ch ^ (r & 7))] = o;
    int id = item_id[r0 + r];
    const float* tsrc = emb + (size_t)id*128 + ch*8;
    float4 t0 = *(const float4*)tsrc;
    float4 t1 = *(const float4*)(tsrc + 4);
    *(float4*)(sTf + r*128 + ch*8)     = t0;
    *(float4*)(sTf + r*128 + ch*8 + 4) = t1;
  }
  __syncthreads();

  // x = a @ nw^T + nb; cat = [x, t, t*x]
  {
    const bf8* A8 = (const bf8*)sA;
    int ct = wave;
    f32x4 acc = {};
    #pragma unroll
    for (int kk = 0; kk < 4; ++kk){
      int kx = (kk*4 + lg) ^ sx;
      bf8 af = A8[lr*16 + kx];
      bf8 bw = *(const bf8*)(NWT + (ct*16+lr)*128 + kk*32 + lg*8);
      acc = MFMA16(af, bw, acc);
    }
    int col = ct*16 + lr;
    float nbc = sNB[col];
    #pragma unroll
    for (int i = 0; i < 4; ++i){
      int r = lg*4 + i;
      float x = acc[i] + nbc;
      float tv = sTf[r*128 + col];
      sCat[swzu(r, col,      48)] = f2bf(x);
      sCat[swzu(r, 128+col,  48)] = f2bf(tv);
      sCat[swzu(r, 256+col,  48)] = f2bf(tv * x);
    }
  }
  __syncthreads();
  // g1 = sig(cat @ dw1 + db1)  (384 -> 512)
  {
    const bf8* C8 = (const bf8*)sCat;
    #pragma unroll
    for (int c = 0; c < 4; ++c){
      int ct = wave + c*8;
      f32x4 acc = {};
      #pragma unroll
      for (int kk = 0; kk < 12; ++kk){
        int kx = (kk*4 + lg) ^ sx;
        bf8 af = C8[lr*48 + kx];
        bf8 bw = *(const bf8*)(D1T + (size_t)(ct*16+lr)*384 + kk*32 + lg*8);
        acc = MFMA16(af, bw, acc);
      }
      int col = ct*16 + lr;
      float bb = sDB1[col];
      #pragma unroll
      for (int i = 0; i < 4; ++i)
        sG1[swzu(lg*4 + i, col, 64)] = f2bf(sigm(acc[i] + bb));
    }
  }
  __syncthreads();
  // g2 = sig(g1 @ dw2 + db2)  (512 -> 256)
  {
    const bf8* G8 = (const bf8*)sG1;
    #pragma unroll
    for (int c = 0; c < 2; ++c){
      int ct = wave + c*8;
      f32x4 acc = {};
      #pragma unroll
      for (int kk = 0; kk < 16; ++kk){
        int kx = (kk*4 + lg) ^ sx;
        bf8 af = G8[lr*64 + kx];
        bf8 bw = *(const bf8*)(D2T + (size_t)(ct*16+lr)*512 + kk*32 + lg*8);
        acc = MFMA16(af, bw, acc);
      }
      int col = ct*16 + lr;
      float bb = sDB2[col];
      #pragma unroll
      for (int i = 0; i < 4; ++i)
        sG2[swzu(lg*4 + i, col, 32)] = f2bf(sigm(acc[i] + bb));
    }
  }
  __syncthreads();
  // g3 = sig(g2 @ dw3 + db3)  (256 -> 128)
  {
    const bf8* G8 = (const bf8*)sG2;
    int ct = wave;
    f32x4 acc = {};
    #pragma unroll
    for (int kk = 0; kk < 8; ++kk){
      int kx = (kk*4 + lg) ^ sx;
      bf8 af = G8[lr*32 + kx];
      bf8 bw = *(const bf8*)(D3T + (size_t)(ct*16+lr)*256 + kk*32 + lg*8);
      acc = MFMA16(af, bw, acc);
    }
    int col = ct*16 + lr;
    float bb = sDB3[col];
    #pragma unroll
    for (int i = 0; i < 4; ++i)
      sG3[swzu(lg*4 + i, col, 16)] = f2bf(sigm(acc[i] + bb));
  }
  __syncthreads();
  // out = g3 @ fw + fb + item_bias
  if (tid < 128){
    int r = tid >> 3, seg = tid & 7;
    float p = 0.f;
    #pragma unroll
    for (int c = 0; c < 16; ++c)
      p += bf2f(sG3[swzu(r, seg*16 + c, 16)]) * sFWd[seg*16 + c];
    p += __shfl_xor(p, 1);
    p += __shfl_xor(p, 2);
    p += __shfl_xor(p, 4);
    if (seg == 0) out[r0 + r] = p + fb[0] + sBias[r];
  }
}

extern "C" void kernel_launch(void* const* d_in, const int* in_sizes, int n_in,
                              void* d_out, int out_size, void* d_ws, size_t ws_size,
                              hipStream_t stream) {
  const int*   in_ids   = (const int*)d_in[0];
  const int*   item_id  = (const int*)d_in[1];
  const float* emb      = (const float*)d_in[2];
  const float* bias_tab = (const float*)d_in[3];
  const float* aw1 = (const float*)d_in[4];
  const float* ab1 = (const float*)d_in[5];
  const float* aw2 = (const float*)d_in[6];
  const float* ab2 = (const float*)d_in[7];
  const float* afw = (const float*)d_in[8];
  const float* afb = (const float*)d_in[9];
  const float* nw  = (const float*)d_in[10];
  const float* nb  = (const float*)d_in[11];
  const float* dw1 = (const float*)d_in[12];
  const float* db1 = (const float*)d_in[13];
  const float* dw2 = (const float*)d_in[14];
  const float* db2 = (const float*)d_in[15];
  const float* dw3 = (const float*)d_in[16];
  const float* db3 = (const float*)d_in[17];
  const float* fw  = (const float*)d_in[18];
  const float* fb  = (const float*)d_in[19];
  float* outp = (float*)d_out;

  char* ws = (char*)d_ws;
  float* attn_raw = (float*)ws;                                   // 1,048,576 B
  unsigned short* WbT  = (unsigned short*)(ws + 1048576);
  unsigned short* WcT  = WbT  + 16384;
  unsigned short* Wsum = WcT  + 16384;
  unsigned short* A2T  = Wsum + 16384;
  unsigned short* NWT  = A2T  + 8192;
  unsigned short* D1T  = NWT  + 16384;
  unsigned short* D2T  = D1T  + 196608;
  unsigned short* D3T  = D2T  + 131072;
  unsigned short* EMBB = D3T  + 32768;   // 100000*128 bf16 = 25.6 MB

  hipLaunchKernelGGL(k_prep, dim3(2048), dim3(256), 0, stream,
                     aw1, aw2, nw, dw1, dw2, dw3, emb,
                     WbT, WcT, Wsum, A2T, NWT, D1T, D2T, D3T, EMBB);
  hipLaunchKernelGGL(k_attn, dim3(2048), dim3(256), 0, stream,
                     in_ids, item_id, emb, EMBB, ab1, ab2, afw, afb,
                     WbT, WcT, Wsum, A2T, attn_raw);
  hipLaunchKernelGGL(k_deep, dim3(128), dim3(512), 0, stream,
                     item_id, emb, bias_tab, nb, db1, db2, db3, fw, fb,
                     NWT, D1T, D2T, D3T, attn_raw, outp);
}

// Round 12
// 111.462 us; speedup vs baseline: 1.0976x; 1.0976x over previous
//
#include <hip/hip_runtime.h>
#include <hip/hip_bf16.h>
#include <stdint.h>

typedef __attribute__((ext_vector_type(8))) short bf8;
typedef __attribute__((ext_vector_type(4))) short bf4;
typedef __attribute__((ext_vector_type(4))) float f32x4;

#define MFMA16(a,b,c) __builtin_amdgcn_mfma_f32_16x16x32_bf16(a,b,c,0,0,0)

__device__ __forceinline__ unsigned short f2bf(float x){
  unsigned int u = __builtin_bit_cast(unsigned int, x);
  u = u + 0x7FFFu + ((u >> 16) & 1u);
  return (unsigned short)(u >> 16);
}
__device__ __forceinline__ unsigned short f2bfb(float x){
  __hip_bfloat16 h = __float2bfloat16(x);
  return __builtin_bit_cast(unsigned short, h);
}
__device__ __forceinline__ float bf2f(unsigned short h){
  unsigned int u = ((unsigned int)h) << 16;
  return __builtin_bit_cast(float, u);
}
// fast sigmoid: no precise-div refinement
__device__ __forceinline__ float sigm(float x){
  return __builtin_amdgcn_rcpf(1.0f + __expf(-x));
}
// swizzled u16 element index for row-major [R][K] bf16 tile, Kd8 = K/8
__device__ __forceinline__ int swzu(int row, int k, int Kd8){
  return (row*Kd8 + ((k>>3) ^ (row & 7)))*8 + (k & 7);
}

// ---- LDS-tiled 64x64 transpose: out[j*R + k] = bf16(in[k*C + j]) ----
__device__ __forceinline__ void tile_transpose(const float* __restrict__ in,
                                               unsigned short* __restrict__ out,
                                               int R, int C, int tb,
                                               float* tile, int tid)
{
  int nkt = R >> 6;
  int kt = tb % nkt, jt = tb / nkt;
  int r0 = tid >> 4, cs = tid & 15;
  #pragma unroll
  for (int i = 0; i < 4; ++i){
    int r = r0 + i*16;
    float4 v = *(const float4*)(in + (size_t)(kt*64 + r)*C + jt*64 + cs*4);
    tile[r*65 + cs*4 + 0] = v.x;
    tile[r*65 + cs*4 + 1] = v.y;
    tile[r*65 + cs*4 + 2] = v.z;
    tile[r*65 + cs*4 + 3] = v.w;
  }
  __syncthreads();
  int j = tid >> 2, ks = tid & 3;
  bf8 o0, o1;
  #pragma unroll
  for (int e = 0; e < 8; ++e){
    o0[e] = (short)f2bf(tile[(ks*16 + e)*65 + j]);
    o1[e] = (short)f2bf(tile[(ks*16 + 8 + e)*65 + j]);
  }
  *(bf8*)(out + (size_t)(jt*64 + j)*R + kt*64 + ks*16)     = o0;
  *(bf8*)(out + (size_t)(jt*64 + j)*R + kt*64 + ks*16 + 8) = o1;
}

// ---------------- prep: weights + emb table to bf16 ----------------
__global__ void k_prep(const float* __restrict__ aw1, const float* __restrict__ aw2,
                       const float* __restrict__ nw, const float* __restrict__ dw1,
                       const float* __restrict__ dw2, const float* __restrict__ dw3,
                       const float* __restrict__ emb,
                       unsigned short* __restrict__ WbT, unsigned short* __restrict__ WcT,
                       unsigned short* __restrict__ Wsum, unsigned short* __restrict__ A2T,
                       unsigned short* __restrict__ NWT, unsigned short* __restrict__ D1T,
                       unsigned short* __restrict__ D2T, unsigned short* __restrict__ D3T,
                       unsigned short* __restrict__ EMBB)
{
  __shared__ float tile[64*65];
  const int bid = blockIdx.x;
  const int tid = threadIdx.x;

  if (bid < 88){
    if (bid < 48)      tile_transpose(dw1, D1T, 384, 512, bid,      tile, tid);
    else if (bid < 80) tile_transpose(dw2, D2T, 512, 256, bid - 48, tile, tid);
    else               tile_transpose(dw3, D3T, 256, 128, bid - 80, tile, tid);
    return;
  }

  int n = (bid - 88)*256 + tid;
  int stride = (gridDim.x - 88)*256;
  // emb fp32 -> bf16 (1.6M chunks of 8)
  for (int i = n; i < 1600000; i += stride){
    const float4* s = (const float4*)(emb + (size_t)i*8);
    float4 a = s[0], b = s[1];
    bf8 o;
    o[0]=(short)f2bf(a.x); o[1]=(short)f2bf(a.y); o[2]=(short)f2bf(a.z); o[3]=(short)f2bf(a.w);
    o[4]=(short)f2bf(b.x); o[5]=(short)f2bf(b.y); o[6]=(short)f2bf(b.z); o[7]=(short)f2bf(b.w);
    ((bf8*)EMBB)[i] = o;
  }
  for (int i = n; i < 16384; i += stride){       // WbT/WcT: [j][k]
    int j = i >> 7, k = i & 127;
    WbT[i] = f2bf(aw1[(128+k)*128 + j]);
    WcT[i] = f2bf(aw1[(256+k)*128 + j]);
  }
  for (int i = n; i < 16384; i += stride){       // Wsum: [j][k]
    int j = i >> 7, k = i & 127;
    Wsum[i] = f2bf(aw1[k*128 + j] + aw1[(256+k)*128 + j]);
  }
  for (int i = n; i < 8192; i += stride){        // A2T: [j(0..63)][k]
    int j = i >> 7, k = i & 127;
    A2T[i] = f2bf(aw2[k*64 + j]);
  }
  for (int i = n; i < 16384; i += stride){       // NWT: [j][k]
    int j = i >> 7, k = i & 127;
    NWT[i] = f2bf(nw[k*128 + j]);
  }
}

// ---------------- attention: R10 champion, no waves-per-EU cap ----------------
__global__ __launch_bounds__(256) void k_attn(
    const int* __restrict__ in_ids, const int* __restrict__ item_id,
    const float* __restrict__ emb, const unsigned short* __restrict__ embb,
    const float* __restrict__ ab1, const float* __restrict__ ab2v,
    const float* __restrict__ afw, const float* __restrict__ afb,
    const unsigned short* __restrict__ WbT, const unsigned short* __restrict__ WcT,
    const unsigned short* __restrict__ Wsum, const unsigned short* __restrict__ A2T,
    float* __restrict__ attn_raw)
{
  __shared__ __align__(16) unsigned short sS[32*128];   // seq tile bf16, swizzled
  __shared__ __align__(16) unsigned short sH[32*128];   // h1^T [r][j], swizzled
  __shared__ float sT[128];
  __shared__ float sC0[128];
  __shared__ float sP2[2][128];
  __shared__ float sPart[4][32];
  __shared__ int   sIds[32];

  const int b = blockIdx.x;
  const int tid = threadIdx.x;
  const int wave = tid >> 6, lane = tid & 63;
  const int lr = lane & 15, lg = lane >> 4;

  const int tgt = item_id[b];
  if (tid < 128) sT[tid] = emb[(size_t)tgt*128 + tid];
  __syncthreads();

  // ---- c0[j] = ab1[j] + sum_k t_k * Wsum[j][k] ----
  {
    int j = tid & 127, hf = tid >> 7;
    const unsigned short* wsrow = Wsum + j*128 + hf*64;
    float p = 0.f;
    #pragma unroll
    for (int c = 0; c < 8; ++c){
      bf8 wv = *(const bf8*)(wsrow + c*8);
      #pragma unroll
      for (int e = 0; e < 8; ++e)
        p += sT[hf*64 + c*8 + e] * bf2f((unsigned short)wv[e]);
    }
    sP2[hf][j] = p;
  }
  __syncthreads();
  if (tid < 128) sC0[tid] = ab1[tid] + sP2[0][tid] + sP2[1][tid];

  // ---- W_eff^T A-fragments in registers: W_eff[k][j] = t_k*Wb[k][j]-Wc[k][j]
  bf8 wfrag[2][4];
  {
    const float4* sT4 = (const float4*)sT;
    #pragma unroll
    for (int mt = 0; mt < 2; ++mt){
      int j = (wave + mt*4)*16 + lr;
      #pragma unroll
      for (int kk = 0; kk < 4; ++kk){
        bf8 wb = *(const bf8*)(WbT + j*128 + kk*32 + lg*8);
        bf8 wc = *(const bf8*)(WcT + j*128 + kk*32 + lg*8);
        float4 t0 = sT4[kk*8 + lg*2];
        float4 t1 = sT4[kk*8 + lg*2 + 1];
        float tv[8] = {t0.x,t0.y,t0.z,t0.w,t1.x,t1.y,t1.z,t1.w};
        bf8 o;
        #pragma unroll
        for (int e = 0; e < 8; ++e)
          o[e] = (short)f2bfb(tv[e]*bf2f((unsigned short)wb[e]) - bf2f((unsigned short)wc[e]));
        wfrag[mt][kk] = o;
      }
    }
  }
  bf8 a2frag[4];
  #pragma unroll
  for (int kk = 0; kk < 4; ++kk)
    a2frag[kk] = *(const bf8*)(A2T + (wave*16+lr)*128 + kk*32 + lg*8);

  float b2r[4], afr[4];
  #pragma unroll
  for (int i = 0; i < 4; ++i){
    int j2 = wave*16 + lg*4 + i;
    b2r[i] = ab2v[j2];
    afr[i] = afw[j2];
  }
  const float afbv = afb[0];
  __syncthreads();
  float c0r[2][4];
  #pragma unroll
  for (int mt = 0; mt < 2; ++mt)
    #pragma unroll
    for (int i = 0; i < 4; ++i)
      c0r[mt][i] = sC0[(wave + mt*4)*16 + lg*4 + i];

  float facc8[8] = {0,0,0,0,0,0,0,0};
  const bf8* S8 = (const bf8*)sS;
  const bf8* H8 = (const bf8*)sH;
  const int rg = tid >> 4, cg = tid & 15;
  const int sxm = lr & 7;
  const int chv = tid & 15;
  const int rowq = tid >> 4;              // 0..15

  // ---- prologue: stage tile 0 into registers ----
  bf8 stg0, stg1; int id0, id1;
  {
    id0 = in_ids[b*200 + rowq];
    stg0 = *(const bf8*)(embb + (size_t)id0*128 + chv*8);
    id1 = in_ids[b*200 + 16 + rowq];
    stg1 = *(const bf8*)(embb + (size_t)id1*128 + chv*8);
  }

  for (int rt = 0; rt < 7; ++rt){
    __syncthreads();   // sS/sIds/sPart free (prev tile fully consumed)
    // ---- commit staged tile to LDS ----
    if (chv == 0){ sIds[rowq] = id0; sIds[16 + rowq] = id1; }
    ((bf8*)sS)[rowq*16 + (chv ^ (rowq & 7))] = stg0;
    {
      int r2 = 16 + rowq;
      ((bf8*)sS)[r2*16 + (chv ^ (r2 & 7))] = stg1;
    }
    // ---- issue prefetch for next tile (latency hides under GEMMs) ----
    if (rt < 6){
      int l0 = (rt+1)*32 + rowq;
      id0 = (l0 < 200) ? in_ids[b*200 + l0] : 0;
      stg0 = *(const bf8*)(embb + (size_t)id0*128 + chv*8);
      int l1 = l0 + 16;
      id1 = (l1 < 200) ? in_ids[b*200 + l1] : 0;
      stg1 = *(const bf8*)(embb + (size_t)id1*128 + chv*8);
    }
    __syncthreads();   // sS ready
    // ---- GEMM1: h1pre^T = mfma(Wfrag, Sfrag) ----
    f32x4 acc1[2][2] = {};
    #pragma unroll
    for (int kk = 0; kk < 4; ++kk){
      int kx = (kk*4 + lg) ^ sxm;
      bf8 s0 = S8[lr*16 + kx];
      bf8 s1 = S8[(16+lr)*16 + kx];
      acc1[0][0] = MFMA16(wfrag[0][kk], s0, acc1[0][0]);
      acc1[0][1] = MFMA16(wfrag[0][kk], s1, acc1[0][1]);
      acc1[1][0] = MFMA16(wfrag[1][kk], s0, acc1[1][0]);
      acc1[1][1] = MFMA16(wfrag[1][kk], s1, acc1[1][1]);
    }
    // write h1^T quads (4 consecutive j -> ds_write_b64)
    #pragma unroll
    for (int mt = 0; mt < 2; ++mt)
      #pragma unroll
      for (int nt = 0; nt < 2; ++nt){
        int r = nt*16 + lr;
        int j0 = (wave + mt*4)*16 + lg*4;
        bf4 q4;
        #pragma unroll
        for (int i = 0; i < 4; ++i)
          q4[i] = (short)f2bfb(sigm(acc1[mt][nt][i] + c0r[mt][i]));
        int idx = (r*16 + ((j0 >> 3) ^ (r & 7)))*8 + (j0 & 7);
        *(bf4*)(sH + idx) = q4;
      }
    __syncthreads();   // sH ready
    // ---- GEMM2: h2^T = mfma(A2frag, Hfrag); score partials in-register ----
    f32x4 acc2[2] = {};
    #pragma unroll
    for (int kk = 0; kk < 4; ++kk){
      int kx = (kk*4 + lg) ^ sxm;
      bf8 h0 = H8[lr*16 + kx];
      bf8 h1f = H8[(16+lr)*16 + kx];
      acc2[0] = MFMA16(a2frag[kk], h0, acc2[0]);
      acc2[1] = MFMA16(a2frag[kk], h1f, acc2[1]);
    }
    float part0 = 0.f, part1 = 0.f;
    #pragma unroll
    for (int i = 0; i < 4; ++i){
      part0 += sigm(acc2[0][i] + b2r[i]) * afr[i];
      part1 += sigm(acc2[1][i] + b2r[i]) * afr[i];
    }
    part0 += __shfl_xor(part0, 16); part0 += __shfl_xor(part0, 32);
    part1 += __shfl_xor(part1, 16); part1 += __shfl_xor(part1, 32);
    if (lg == 0){ sPart[wave][lr] = part0; sPart[wave][16+lr] = part1; }
    __syncthreads();   // sPart ready
    // ---- attn += score * S ----
    #pragma unroll
    for (int q = 0; q < 2; ++q){
      int r = rg*2 + q;
      int l = rt*32 + r;
      float sc = sPart[0][r] + sPart[1][r] + sPart[2][r] + sPart[3][r] + afbv;
      sc = (l < 200 && sIds[r] != 0) ? sc : 0.f;
      bf8 v = S8[r*16 + (cg ^ (r & 7))];
      #pragma unroll
      for (int e = 0; e < 8; ++e)
        facc8[e] += sc * bf2f((unsigned short)v[e]);
    }
  }
  // ---- final reduce over 16 row-groups (reuse sS as float scratch) ----
  __syncthreads();
  float* red = (float*)sS;
  #pragma unroll
  for (int e = 0; e < 8; ++e) red[tid*8 + e] = facc8[e];
  __syncthreads();
  if (tid < 128){
    float s = 0.f;
    #pragma unroll
    for (int g = 0; g < 16; ++g) s += red[g*128 + tid];
    attn_raw[(size_t)b*128 + tid] = s;
  }
}

// ---------------- deep MLP (512 threads, 8 waves) ----------------
__global__ __launch_bounds__(512) void k_deep(
    const int* __restrict__ item_id, const float* __restrict__ emb,
    const float* __restrict__ bias_tab,
    const float* __restrict__ nbv,
    const float* __restrict__ db1, const float* __restrict__ db2,
    const float* __restrict__ db3, const float* __restrict__ fw,
    const float* __restrict__ fb,
    const unsigned short* __restrict__ NWT, const unsigned short* __restrict__ D1T,
    const unsigned short* __restrict__ D2T, const unsigned short* __restrict__ D3T,
    const float* __restrict__ attn_raw, float* __restrict__ out)
{
  __shared__ __align__(16) unsigned short sA[16*128];
  __shared__ float sTf[16*128];
  __shared__ __align__(16) unsigned short sCat[16*384];
  __shared__ __align__(16) unsigned short sG1[16*512];
  __shared__ __align__(16) unsigned short sG2[16*256];
  __shared__ __align__(16) unsigned short sG3[16*128];
  __shared__ float sNB[128], sDB1[512], sDB2[256], sDB3[128], sFWd[128];
  __shared__ float sBias[16];

  const int r0 = blockIdx.x * 16;
  const int tid = threadIdx.x;
  const int wave = tid >> 6, lane = tid & 63;
  const int lr = lane & 15, lg = lane >> 4;
  const int sx = lr & 7;

  if (tid < 128){ sNB[tid] = nbv[tid]; sDB3[tid] = db3[tid]; sFWd[tid] = fw[tid]; }
  sDB1[tid] = db1[tid];
  if (tid < 256) sDB2[tid] = db2[tid];
  if (tid < 16) sBias[tid] = bias_tab[item_id[r0 + tid]];

  if (tid < 256){
    int r = tid >> 4, ch = tid & 15;
    const float* asrc = attn_raw + (size_t)(r0 + r)*128 + ch*8;
    float4 v0 = *(const float4*)asrc;
    float4 v1 = *(const float4*)(asrc + 4);
    bf8 o;
    o[0]=(short)f2bf(v0.x); o[1]=(short)f2bf(v0.y); o[2]=(short)f2bf(v0.z); o[3]=(short)f2bf(v0.w);
    o[4]=(short)f2bf(v1.x); o[5]=(short)f2bf(v1.y); o[6]=(short)f2bf(v1.z); o[7]=(short)f2bf(v1.w);
    ((bf8*)sA)[r*16 + (ch ^ (r & 7))] = o;
    int id = item_id[r0 + r];
    const float* tsrc = emb + (size_t)id*128 + ch*8;
    float4 t0 = *(const float4*)tsrc;
    float4 t1 = *(const float4*)(tsrc + 4);
    *(float4*)(sTf + r*128 + ch*8)     = t0;
    *(float4*)(sTf + r*128 + ch*8 + 4) = t1;
  }
  __syncthreads();

  // x = a @ nw^T + nb; cat = [x, t, t*x]
  {
    const bf8* A8 = (const bf8*)sA;
    int ct = wave;
    f32x4 acc = {};
    #pragma unroll
    for (int kk = 0; kk < 4; ++kk){
      int kx = (kk*4 + lg) ^ sx;
      bf8 af = A8[lr*16 + kx];
      bf8 bw = *(const bf8*)(NWT + (ct*16+lr)*128 + kk*32 + lg*8);
      acc = MFMA16(af, bw, acc);
    }
    int col = ct*16 + lr;
    float nbc = sNB[col];
    #pragma unroll
    for (int i = 0; i < 4; ++i){
      int r = lg*4 + i;
      float x = acc[i] + nbc;
      float tv = sTf[r*128 + col];
      sCat[swzu(r, col,      48)] = f2bf(x);
      sCat[swzu(r, 128+col,  48)] = f2bf(tv);
      sCat[swzu(r, 256+col,  48)] = f2bf(tv * x);
    }
  }
  __syncthreads();
  // g1 = sig(cat @ dw1 + db1)  (384 -> 512)
  {
    const bf8* C8 = (const bf8*)sCat;
    #pragma unroll
    for (int c = 0; c < 4; ++c){
      int ct = wave + c*8;
      f32x4 acc = {};
      #pragma unroll
      for (int kk = 0; kk < 12; ++kk){
        int kx = (kk*4 + lg) ^ sx;
        bf8 af = C8[lr*48 + kx];
        bf8 bw = *(const bf8*)(D1T + (size_t)(ct*16+lr)*384 + kk*32 + lg*8);
        acc = MFMA16(af, bw, acc);
      }
      int col = ct*16 + lr;
      float bb = sDB1[col];
      #pragma unroll
      for (int i = 0; i < 4; ++i)
        sG1[swzu(lg*4 + i, col, 64)] = f2bf(sigm(acc[i] + bb));
    }
  }
  __syncthreads();
  // g2 = sig(g1 @ dw2 + db2)  (512 -> 256)
  {
    const bf8* G8 = (const bf8*)sG1;
    #pragma unroll
    for (int c = 0; c < 2; ++c){
      int ct = wave + c*8;
      f32x4 acc = {};
      #pragma unroll
      for (int kk = 0; kk < 16; ++kk){
        int kx = (kk*4 + lg) ^ sx;
        bf8 af = G8[lr*64 + kx];
        bf8 bw = *(const bf8*)(D2T + (size_t)(ct*16+lr)*512 + kk*32 + lg*8);
        acc = MFMA16(af, bw, acc);
      }
      int col = ct*16 + lr;
      float bb = sDB2[col];
      #pragma unroll
      for (int i = 0; i < 4; ++i)
        sG2[swzu(lg*4 + i, col, 32)] = f2bf(sigm(acc[i] + bb));
    }
  }
  __syncthreads();
  // g3 = sig(g2 @ dw3 + db3)  (256 -> 128)
  {
    const bf8* G8 = (const bf8*)sG2;
    int ct = wave;
    f32x4 acc = {};
    #pragma unroll
    for (int kk = 0; kk < 8; ++kk){
      int kx = (kk*4 + lg) ^ sx;
      bf8 af = G8[lr*32 + kx];
      bf8 bw = *(const bf8*)(D3T + (size_t)(ct*16+lr)*256 + kk*32 + lg*8);
      acc = MFMA16(af, bw, acc);
    }
    int col = ct*16 + lr;
    float bb = sDB3[col];
    #pragma unroll
    for (int i = 0; i < 4; ++i)
      sG3[swzu(lg*4 + i, col, 16)] = f2bf(sigm(acc[i] + bb));
  }
  __syncthreads();
  // out = g3 @ fw + fb + item_bias
  if (tid < 128){
    int r = tid >> 3, seg = tid & 7;
    float p = 0.f;
    #pragma unroll
    for (int c = 0; c < 16; ++c)
      p += bf2f(sG3[swzu(r, seg*16 + c, 16)]) * sFWd[seg*16 + c];
    p += __shfl_xor(p, 1);
    p += __shfl_xor(p, 2);
    p += __shfl_xor(p, 4);
    if (seg == 0) out[r0 + r] = p + fb[0] + sBias[r];
  }
}

extern "C" void kernel_launch(void* const* d_in, const int* in_sizes, int n_in,
                              void* d_out, int out_size, void* d_ws, size_t ws_size,
                              hipStream_t stream) {
  const int*   in_ids   = (const int*)d_in[0];
  const int*   item_id  = (const int*)d_in[1];
  const float* emb      = (const float*)d_in[2];
  const float* bias_tab = (const float*)d_in[3];
  const float* aw1 = (const float*)d_in[4];
  const float* ab1 = (const float*)d_in[5];
  const float* aw2 = (const float*)d_in[6];
  const float* ab2 = (const float*)d_in[7];
  const float* afw = (const float*)d_in[8];
  const float* afb = (const float*)d_in[9];
  const float* nw  = (const float*)d_in[10];
  const float* nb  = (const float*)d_in[11];
  const float* dw1 = (const float*)d_in[12];
  const float* db1 = (const float*)d_in[13];
  const float* dw2 = (const float*)d_in[14];
  const float* db2 = (const float*)d_in[15];
  const float* dw3 = (const float*)d_in[16];
  const float* db3 = (const float*)d_in[17];
  const float* fw  = (const float*)d_in[18];
  const float* fb  = (const float*)d_in[19];
  float* outp = (float*)d_out;

  char* ws = (char*)d_ws;
  float* attn_raw = (float*)ws;                                   // 1,048,576 B
  unsigned short* WbT  = (unsigned short*)(ws + 1048576);
  unsigned short* WcT  = WbT  + 16384;
  unsigned short* Wsum = WcT  + 16384;
  unsigned short* A2T  = Wsum + 16384;
  unsigned short* NWT  = A2T  + 8192;
  unsigned short* D1T  = NWT  + 16384;
  unsigned short* D2T  = D1T  + 196608;
  unsigned short* D3T  = D2T  + 131072;
  unsigned short* EMBB = D3T  + 32768;   // 100000*128 bf16 = 25.6 MB

  hipLaunchKernelGGL(k_prep, dim3(2048), dim3(256), 0, stream,
                     aw1, aw2, nw, dw1, dw2, dw3, emb,
                     WbT, WcT, Wsum, A2T, NWT, D1T, D2T, D3T, EMBB);
  hipLaunchKernelGGL(k_attn, dim3(2048), dim3(256), 0, stream,
                     in_ids, item_id, emb, EMBB, ab1, ab2, afw, afb,
                     WbT, WcT, Wsum, A2T, attn_raw);
  hipLaunchKernelGGL(k_deep, dim3(128), dim3(512), 0, stream,
                     item_id, emb, bias_tab, nb, db1, db2, db3, fw, fb,
                     NWT, D1T, D2T, D3T, attn_raw, outp);
}